// Round 9
// baseline (279.092 us; speedup 1.0000x reference)
//
#include <hip/hip_runtime.h>

#define B_  4
#define C_  256
#define C8_ 32
#define N_  4096   // H*W

#define KI 64      // i per iteration
#define SPLITS 2   // i-range splits

typedef __attribute__((ext_vector_type(8)))  short bf16x8;   // MFMA A/B frag (8 bf16)
typedef __attribute__((ext_vector_type(16))) float f32x16;   // 32x32 C/D frag

union FragAB { bf16x8 v; unsigned short u[8]; unsigned u32[4]; };

__device__ __forceinline__ unsigned short f2bf(float x) {
    unsigned u = __float_as_uint(x);
    unsigned r = u + 0x7FFFu + ((u >> 16) & 1u);   // RNE
    return (unsigned short)(r >> 16);
}
__device__ __forceinline__ unsigned pack2bf(float a, float b) {
    return (unsigned)f2bf(a) | ((unsigned)f2bf(b) << 16);
}
__device__ __forceinline__ float bf2f(unsigned short h) {
    return __uint_as_float(((unsigned)h) << 16);
}

// ---------------- prep: W concat -> bf16 [320][256] ----------------
__global__ __launch_bounds__(256) void prep_w_kernel(
    const float* __restrict__ Wq, const float* __restrict__ Wk,
    const float* __restrict__ Wv, unsigned short* __restrict__ Wbf)
{
    int idx = (blockIdx.x * 256 + threadIdx.x) * 4;
    int row = idx >> 8;
    int col = idx & 255;
    const float* src; int r;
    if (row < 32)      { src = Wq; r = row;      }
    else if (row < 64) { src = Wk; r = row - 32; }
    else               { src = Wv; r = row - 64; }
    float4 v = *(const float4*)&src[r * 256 + col];
    uint2 o; o.x = pack2bf(v.x, v.y); o.y = pack2bf(v.z, v.w);
    *(uint2*)&Wbf[idx] = o;
}

// ---------------- prep: x [b][c][n] fp32 -> xT [b][n][c] bf16 ----------------
__global__ __launch_bounds__(256) void prep_x_kernel(
    const float* __restrict__ x, unsigned short* __restrict__ xT)
{
    __shared__ unsigned short T[64][66];
    int t  = threadIdx.x;
    int b  = blockIdx.z;
    int c0 = blockIdx.y * 64;
    int n0 = blockIdx.x * 64;
    const float* xb = x + (size_t)b * C_ * N_;
    int n_l = t & 63, c_l = t >> 6;
#pragma unroll
    for (int q = 0; q < 16; ++q) {
        int c = c_l * 16 + q;
        T[n_l][c] = f2bf(xb[(size_t)(c0 + c) * N_ + n0 + n_l]);
    }
    __syncthreads();
    unsigned short* xTb = xT + (size_t)b * N_ * C_;
    int c_l2 = t & 63, nb = t >> 6;
#pragma unroll
    for (int q = 0; q < 16; ++q) {
        int n = nb * 16 + q;
        xTb[(size_t)(n0 + n) * C_ + c0 + c_l2] = T[n][c_l2];
    }
}

// ---------------- MFMA projection ----------------
// f written transposed: fTg[b][n][32] so flash 16B-loads score A-frags.
__global__ __launch_bounds__(256) void proj_mfma_kernel(
    const unsigned short* __restrict__ Wbf, const unsigned short* __restrict__ xT,
    unsigned short* __restrict__ fTg, unsigned short* __restrict__ g,
    unsigned short* __restrict__ hv)
{
    int t = threadIdx.x, w = t >> 6, lane = t & 63;
    int half = lane >> 5, l31 = lane & 31;
    int b  = blockIdx.y;
    int n0 = blockIdx.x * 32;

    const unsigned short* xb = xT + ((size_t)b * N_ + n0 + l31) * C_;
    int nm = (w < 2) ? 3 : 2;
    int mt0 = w, mt1 = w + 4, mt2 = w + 8;

    f32x16 acc[3];
#pragma unroll
    for (int a = 0; a < 3; ++a) acc[a] = (f32x16)0.f;

#pragma unroll
    for (int ks = 0; ks < 16; ++ks) {
        int kofs = ks * 16 + half * 8;
        bf16x8 bfr = *(const bf16x8*)&xb[kofs];
        bf16x8 a0 = *(const bf16x8*)&Wbf[(size_t)(mt0 * 32 + l31) * 256 + kofs];
        acc[0] = __builtin_amdgcn_mfma_f32_32x32x16_bf16(a0, bfr, acc[0], 0, 0, 0);
        bf16x8 a1 = *(const bf16x8*)&Wbf[(size_t)(mt1 * 32 + l31) * 256 + kofs];
        acc[1] = __builtin_amdgcn_mfma_f32_32x32x16_bf16(a1, bfr, acc[1], 0, 0, 0);
        if (nm == 3) {
            bf16x8 a2 = *(const bf16x8*)&Wbf[(size_t)(mt2 * 32 + l31) * 256 + kofs];
            acc[2] = __builtin_amdgcn_mfma_f32_32x32x16_bf16(a2, bfr, acc[2], 0, 0, 0);
        }
    }

    unsigned short* gb = g  + (size_t)b * C8_ * N_;
    unsigned short* hb = hv + (size_t)b * C_  * N_;
#pragma unroll
    for (int im = 0; im < 3; ++im) {
        if (im >= nm) break;
        int mt = (im == 0) ? mt0 : (im == 1) ? mt1 : mt2;
#pragma unroll
        for (int r = 0; r < 16; ++r) {
            int R = mt * 32 + (r & 3) + 8 * (r >> 2) + 4 * half;
            unsigned short v = f2bf(acc[im][r]);
            if (R < 32)       fTg[((size_t)b * N_ + n0 + l31) * 32 + R] = v;
            else if (R < 64)  gb[(size_t)(R - 32) * N_ + n0 + l31] = v;
            else              hb[(size_t)(R - 64) * N_ + n0 + l31] = v;
        }
    }
}

// ---------------- MFMA flash attention, v5: in-register P, lean regs ------
// Block: 256c x 64j. 4 waves: cg=w>>1 (c-half 128), jg=w&1 (j-32 group).
// Wave tile: 128c x 32j -> acc[4] (64 AGPRs). Scores duplicated across cg.
// Score D[col=j=l31] is lane-aligned with PV B-operand [n=j=l31]; row/reg
// mismatch fixed with 8 shfl_xor(.,32) per 32x32 tile:
//   o_q = pack(p[2q],p[2q+1]), e_q = shfl_xor(o_q,32)
//   pf[kb] = half ? {e(4kb+2),e(4kb+3),o(4kb+2),o(4kb+3)}
//                 : {o(4kb+0),o(4kb+1),e(4kb+0),e(4kb+1)}
// No pT LDS. hvT (32 KB) XOR-swizzled 16B units (unit ^ (c&7)).
// 2 barriers per KI=64 iter, 20 MFMAs/wave between barrier pairs.
__global__ __launch_bounds__(256, 2) void flash_kernel(
    const unsigned short* __restrict__ fTg, const unsigned short* __restrict__ g,
    const unsigned short* __restrict__ hv, unsigned short* __restrict__ o_part,
    float* __restrict__ l_part)
{
    __shared__ unsigned short hvT[256][64];   // [c][i], 128B rows, swizzled units

    int t    = threadIdx.x;
    int w    = t >> 6;
    int lane = t & 63;
    int half = lane >> 5;
    int l31  = lane & 31;
    int cg   = w >> 1;
    int jg   = w & 1;

    int j0 = blockIdx.x * 64;
    int s  = blockIdx.y;
    int b  = blockIdx.z;
    int bs = b * SPLITS + s;
    int jb = j0 + jg * 32;

    const unsigned short* fb = fTg + (size_t)b * N_ * 32;
    const unsigned short* gb = g   + (size_t)b * C8_ * N_;
    const unsigned short* hb = hv  + (size_t)b * C_ * N_;

    // staging map: 8 lanes per row, 16B per lane (128B contiguous segments)
    int su  = t & 7;            // 16B unit within row
    int sc0 = t >> 3;           // row 0..31, +32 per rep
    int ssw = su ^ (sc0 & 7);   // swizzled unit ((sc0+32*rep)&7 == sc0&7)

    // g B-frags for wave's 32 j (k = channel)
    FragAB gf[2];
#pragma unroll
    for (int ks = 0; ks < 2; ++ks)
#pragma unroll
        for (int r = 0; r < 8; ++r)
            gf[ks].u[r] = gb[(size_t)(ks * 16 + half * 8 + r) * N_ + jb + l31];

    f32x16 acc[4];   // ct
#pragma unroll
    for (int a = 0; a < 4; ++a) acc[a] = (f32x16)0.f;
    float lacc = 0.f;

    int i_begin = s * (N_ / SPLITS);

    for (int ii = 0; ii < (N_ / SPLITS) / KI; ++ii) {
        int i0 = i_begin + ii * KI;

        // ---- issue hv staging loads (overlap with barrier wait) ----
        uint4 sv[8];
#pragma unroll
        for (int rep = 0; rep < 8; ++rep)
            sv[rep] = *(const uint4*)&hb[(size_t)(sc0 + 32 * rep) * N_ + i0 + su * 8];

        __syncthreads();   // B1: prior iter's PV reads done
#pragma unroll
        for (int rep = 0; rep < 8; ++rep)
            *(uint4*)&hvT[sc0 + 32 * rep][ssw * 8] = sv[rep];
        __syncthreads();   // B2: hvT visible

#pragma unroll
        for (int it = 0; it < 2; ++it) {
            // ---- scores: i-sub [i0+it*32, +32) x wave's 32 j ----
            bf16x8 af0 = *(const bf16x8*)&fb[(size_t)(i0 + it * 32 + l31) * 32 + half * 8];
            bf16x8 af1 = *(const bf16x8*)&fb[(size_t)(i0 + it * 32 + l31) * 32 + 16 + half * 8];
            f32x16 sacc = __builtin_amdgcn_mfma_f32_32x32x16_bf16(
                af0, gf[0].v, (f32x16)0.f, 0, 0, 0);
            sacc = __builtin_amdgcn_mfma_f32_32x32x16_bf16(
                af1, gf[1].v, sacc, 0, 0, 0);
            float p[16];
#pragma unroll
            for (int r = 0; r < 16; ++r) {
                p[r] = __expf(sacc[r]);
                lacc += p[r];
            }
            unsigned o[8], e[8];
#pragma unroll
            for (int q = 0; q < 8; ++q) {
                o[q] = pack2bf(p[2 * q], p[2 * q + 1]);
                e[q] = __shfl_xor((int)o[q], 32);
            }
            FragAB pf[2];
#pragma unroll
            for (int kb = 0; kb < 2; ++kb) {
                pf[kb].u32[0] = half ? e[4 * kb + 2] : o[4 * kb + 0];
                pf[kb].u32[1] = half ? e[4 * kb + 3] : o[4 * kb + 1];
                pf[kb].u32[2] = half ? o[4 * kb + 2] : e[4 * kb + 0];
                pf[kb].u32[3] = half ? o[4 * kb + 3] : e[4 * kb + 1];
            }
            // ---- PV: c-range [cg*128, +128) x wave's 32 j ----
#pragma unroll
            for (int kb = 0; kb < 2; ++kb) {
                int unit = it * 4 + kb * 2 + half;
#pragma unroll
                for (int ct = 0; ct < 4; ++ct) {
                    int c = cg * 128 + ct * 32 + l31;
                    bf16x8 afr = *(const bf16x8*)&hvT[c][(unit ^ (c & 7)) * 8];
                    acc[ct] = __builtin_amdgcn_mfma_f32_32x32x16_bf16(
                        afr, pf[kb].v, acc[ct], 0, 0, 0);
                }
            }
        }
    }

    // ---- write bf16 partials ----
    unsigned short* ob = o_part + (size_t)bs * C_ * N_;
#pragma unroll
    for (int ct = 0; ct < 4; ++ct) {
        f32x16 a = acc[ct];
#pragma unroll
        for (int r = 0; r < 16; ++r) {
            int c = cg * 128 + ct * 32 + (r & 3) + 8 * (r >> 2) + 4 * half;
            int j = jb + l31;
            ob[(size_t)c * N_ + j] = f2bf(a[r]);
        }
    }
    // ---- column sums (cg==0 waves; halves hold complementary i-rows) ----
    if (cg == 0) {
        float lsum = lacc + __shfl_xor(lacc, 32);
        if (half == 0)
            l_part[(size_t)bs * N_ + jb + l31] = lsum;
    }
}

// ---------------- combine: sum splits, normalize, residual ----------------
__global__ __launch_bounds__(256) void combine_kernel(
    const unsigned short* __restrict__ o_part, const float* __restrict__ l_part,
    const float* __restrict__ x, const float* __restrict__ gamma,
    float* __restrict__ out)
{
    int j = blockIdx.x * 256 + threadIdx.x;
    int b = blockIdx.z;
    float l = 0.f;
#pragma unroll
    for (int s = 0; s < SPLITS; ++s)
        l += l_part[(size_t)(b * SPLITS + s) * N_ + j];
    float inv = 1.f / l;
    float gm = gamma[0];
#pragma unroll
    for (int cc = 0; cc < 4; ++cc) {
        int c = blockIdx.y * 4 + cc;
        float o = 0.f;
#pragma unroll
        for (int s = 0; s < SPLITS; ++s)
            o += bf2f(o_part[((size_t)(b * SPLITS + s) * C_ + c) * N_ + j]);
        size_t idx = ((size_t)b * C_ + c) * N_ + j;
        out[idx] = gm * o * inv + x[idx];
    }
}

extern "C" void kernel_launch(void* const* d_in, const int* in_sizes, int n_in,
                              void* d_out, int out_size, void* d_ws, size_t ws_size,
                              hipStream_t stream) {
    const float* x     = (const float*)d_in[0];
    const float* Wq    = (const float*)d_in[1];
    const float* Wk    = (const float*)d_in[2];
    const float* Wv    = (const float*)d_in[3];
    const float* gamma = (const float*)d_in[4];
    float* out = (float*)d_out;

    char* ws = (char*)d_ws;
    unsigned short* o_part = (unsigned short*)ws;                     // 16.8 MB bf16
    float* l_part = (float*)(o_part + (size_t)SPLITS * B_ * C_ * N_); // 128 KB
    unsigned short* fTg = (unsigned short*)(l_part + (size_t)SPLITS * B_ * N_); // 1 MB
    unsigned short* g   = fTg + (size_t)B_ * C8_ * N_;                // 1 MB
    unsigned short* hv  = g   + (size_t)B_ * C8_ * N_;                // 8 MB
    unsigned short* Wbf = hv  + (size_t)B_ * C_  * N_;                // 160 KB
    unsigned short* xT  = Wbf + (size_t)(C_ + 2 * C8_) * C_;          // 8.4 MB

    prep_w_kernel<<<dim3(80), 256, 0, stream>>>(Wq, Wk, Wv, Wbf);
    prep_x_kernel<<<dim3(N_ / 64, C_ / 64, B_), 256, 0, stream>>>(x, xT);

    proj_mfma_kernel<<<dim3(N_ / 32, B_), 256, 0, stream>>>(Wbf, xT, fTg, g, hv);

    flash_kernel<<<dim3(N_ / 64, SPLITS, B_), 256, 0, stream>>>(
        fTg, g, hv, o_part, l_part);

    combine_kernel<<<dim3(N_ / 256, C_ / 4, B_), 256, 0, stream>>>(o_part, l_part, x, gamma, out);
}

// Round 10
// 174.007 us; speedup vs baseline: 1.6039x; 1.6039x over previous
//
#include <hip/hip_runtime.h>

#define B_  4
#define C_  256
#define C8_ 32
#define N_  4096   // H*W

#define KI 64      // i per iteration
#define SPLITS 2   // i-range splits

typedef __attribute__((ext_vector_type(8)))  short bf16x8;   // MFMA A/B frag (8 bf16)
typedef __attribute__((ext_vector_type(16))) float f32x16;   // 32x32 C/D frag
typedef __attribute__((ext_vector_type(4)))  unsigned u32x4;

union FragAB { bf16x8 v; unsigned short u[8]; unsigned u32[4]; };

__device__ __forceinline__ unsigned short f2bf(float x) {
    unsigned u = __float_as_uint(x);
    unsigned r = u + 0x7FFFu + ((u >> 16) & 1u);   // RNE
    return (unsigned short)(r >> 16);
}
__device__ __forceinline__ unsigned pack2bf(float a, float b) {
    return (unsigned)f2bf(a) | ((unsigned)f2bf(b) << 16);
}
__device__ __forceinline__ float bf2f(unsigned short h) {
    return __uint_as_float(((unsigned)h) << 16);
}
__device__ __forceinline__ void async_load16(const unsigned short* gp, unsigned short* lp) {
    __builtin_amdgcn_global_load_lds(
        (const __attribute__((address_space(1))) void*)gp,
        (__attribute__((address_space(3))) void*)lp, 16, 0, 0);
}

// ---------------- prep: W concat -> bf16 [320][256] ----------------
__global__ __launch_bounds__(256) void prep_w_kernel(
    const float* __restrict__ Wq, const float* __restrict__ Wk,
    const float* __restrict__ Wv, unsigned short* __restrict__ Wbf)
{
    int idx = (blockIdx.x * 256 + threadIdx.x) * 4;
    int row = idx >> 8;
    int col = idx & 255;
    const float* src; int r;
    if (row < 32)      { src = Wq; r = row;      }
    else if (row < 64) { src = Wk; r = row - 32; }
    else               { src = Wv; r = row - 64; }
    float4 v = *(const float4*)&src[r * 256 + col];
    uint2 o; o.x = pack2bf(v.x, v.y); o.y = pack2bf(v.z, v.w);
    *(uint2*)&Wbf[idx] = o;
}

// ---------------- prep: x [b][c][n] fp32 -> xT [b][n][c] bf16 ----------------
__global__ __launch_bounds__(256) void prep_x_kernel(
    const float* __restrict__ x, unsigned short* __restrict__ xT)
{
    __shared__ unsigned short T[64][66];
    int t  = threadIdx.x;
    int b  = blockIdx.z;
    int c0 = blockIdx.y * 64;
    int n0 = blockIdx.x * 64;
    const float* xb = x + (size_t)b * C_ * N_;
    int n_l = t & 63, c_l = t >> 6;
#pragma unroll
    for (int q = 0; q < 16; ++q) {
        int c = c_l * 16 + q;
        T[n_l][c] = f2bf(xb[(size_t)(c0 + c) * N_ + n0 + n_l]);
    }
    __syncthreads();
    unsigned short* xTb = xT + (size_t)b * N_ * C_;
    int c_l2 = t & 63, nb = t >> 6;
#pragma unroll
    for (int q = 0; q < 16; ++q) {
        int n = nb * 16 + q;
        xTb[(size_t)(n0 + n) * C_ + c0 + c_l2] = T[n][c_l2];
    }
}

// ---------------- MFMA projection ----------------
// f written transposed: fTg[b][n][32] so flash 16B-loads score A-frags.
__global__ __launch_bounds__(256) void proj_mfma_kernel(
    const unsigned short* __restrict__ Wbf, const unsigned short* __restrict__ xT,
    unsigned short* __restrict__ fTg, unsigned short* __restrict__ g,
    unsigned short* __restrict__ hv)
{
    int t = threadIdx.x, w = t >> 6, lane = t & 63;
    int half = lane >> 5, l31 = lane & 31;
    int b  = blockIdx.y;
    int n0 = blockIdx.x * 32;

    const unsigned short* xb = xT + ((size_t)b * N_ + n0 + l31) * C_;
    int nm = (w < 2) ? 3 : 2;
    int mt0 = w, mt1 = w + 4, mt2 = w + 8;

    f32x16 acc[3];
#pragma unroll
    for (int a = 0; a < 3; ++a) acc[a] = (f32x16)0.f;

#pragma unroll
    for (int ks = 0; ks < 16; ++ks) {
        int kofs = ks * 16 + half * 8;
        bf16x8 bfr = *(const bf16x8*)&xb[kofs];
        bf16x8 a0 = *(const bf16x8*)&Wbf[(size_t)(mt0 * 32 + l31) * 256 + kofs];
        acc[0] = __builtin_amdgcn_mfma_f32_32x32x16_bf16(a0, bfr, acc[0], 0, 0, 0);
        bf16x8 a1 = *(const bf16x8*)&Wbf[(size_t)(mt1 * 32 + l31) * 256 + kofs];
        acc[1] = __builtin_amdgcn_mfma_f32_32x32x16_bf16(a1, bfr, acc[1], 0, 0, 0);
        if (nm == 3) {
            bf16x8 a2 = *(const bf16x8*)&Wbf[(size_t)(mt2 * 32 + l31) * 256 + kofs];
            acc[2] = __builtin_amdgcn_mfma_f32_32x32x16_bf16(a2, bfr, acc[2], 0, 0, 0);
        }
    }

    unsigned short* gb = g  + (size_t)b * C8_ * N_;
    unsigned short* hb = hv + (size_t)b * C_  * N_;
#pragma unroll
    for (int im = 0; im < 3; ++im) {
        if (im >= nm) break;
        int mt = (im == 0) ? mt0 : (im == 1) ? mt1 : mt2;
#pragma unroll
        for (int r = 0; r < 16; ++r) {
            int R = mt * 32 + (r & 3) + 8 * (r >> 2) + 4 * half;
            unsigned short v = f2bf(acc[im][r]);
            if (R < 32)       fTg[((size_t)b * N_ + n0 + l31) * 32 + R] = v;
            else if (R < 64)  gb[(size_t)(R - 32) * N_ + n0 + l31] = v;
            else              hb[(size_t)(R - 64) * N_ + n0 + l31] = v;
        }
    }
}

// ---------------- MFMA flash attention, v6: async DMA + in-register P -----
// Block: 256c x 64j. 4 waves: cg=w>>1 (c-half 128), jg=w&1 (j-32 group).
// hv staged via global_load_lds width=16 into double-buffered hvT (2x32 KB);
// XOR swizzle folded into the GLOBAL address: hvT[c][u] holds i-chunk u^(c&7)
// (lane l of a wave-rep fetches chunk (l&7)^(l>>3) of row w*8+(l>>3)+32*rep).
// One barrier per KI=64 iteration; DMA for iter ii+1 overlaps compute of ii.
// Scores produce D[col=j=l31], lane-aligned with PV B-operand; row/reg fixed
// with 8 shfl_xor(.,32). All temporaries scalar + bit_cast (no scratch).
__global__ __launch_bounds__(256, 2) void flash_kernel(
    const unsigned short* __restrict__ fTg, const unsigned short* __restrict__ g,
    const unsigned short* __restrict__ hv, unsigned short* __restrict__ o_part,
    float* __restrict__ l_part)
{
    __shared__ unsigned short hvT[2][256][64];   // 64 KB

    int t    = threadIdx.x;
    int w    = t >> 6;
    int lane = t & 63;
    int half = lane >> 5;
    int l31  = lane & 31;
    int cg   = w >> 1;
    int jg   = w & 1;

    int j0 = blockIdx.x * 64;
    int s  = blockIdx.y;
    int b  = blockIdx.z;
    int bs = b * SPLITS + s;
    int jb = j0 + jg * 32;

    const unsigned short* fb = fTg + (size_t)b * N_ * 32;
    const unsigned short* gb = g   + (size_t)b * C8_ * N_;
    const unsigned short* hb = hv  + (size_t)b * C_ * N_;

    // DMA map: lane l -> row w*8 + (l>>3) (+32/rep), global chunk (l&7)^(l>>3)
    int srow = lane >> 3;
    int sug  = (lane & 7) ^ srow;
    const unsigned short* hsrc = hb + (size_t)(w * 8 + srow) * N_ + sug * 8;

    // g B-frags for wave's 32 j (k = channel)
    bf16x8 gf0, gf1;
#pragma unroll
    for (int r = 0; r < 8; ++r) {
        gf0[r] = (short)gb[(size_t)(half * 8 + r) * N_ + jb + l31];
        gf1[r] = (short)gb[(size_t)(16 + half * 8 + r) * N_ + jb + l31];
    }

    f32x16 acc[4];   // ct
#pragma unroll
    for (int a = 0; a < 4; ++a) acc[a] = (f32x16)0.f;
    float lacc = 0.f;

    int i_begin = s * (N_ / SPLITS);
    const int NIT = (N_ / SPLITS) / KI;   // 32

    // prologue: stage buf0
#pragma unroll
    for (int rep = 0; rep < 8; ++rep)
        async_load16(hsrc + (size_t)rep * 32 * N_ + i_begin,
                     &hvT[0][rep * 32 + w * 8][0]);

    for (int ii = 0; ii < NIT; ++ii) {
        int i0  = i_begin + ii * KI;
        int cur = ii & 1;

        __syncthreads();   // drains this wave's DMA (vmcnt 0) + all waves synced

        if (ii + 1 < NIT) {
#pragma unroll
            for (int rep = 0; rep < 8; ++rep)
                async_load16(hsrc + (size_t)rep * 32 * N_ + i0 + KI,
                             &hvT[cur ^ 1][rep * 32 + w * 8][0]);
        }

#pragma unroll
        for (int it = 0; it < 2; ++it) {
            // ---- scores: i-sub [i0+it*32, +32) x wave's 32 j ----
            bf16x8 af0 = *(const bf16x8*)&fb[(size_t)(i0 + it * 32 + l31) * 32 + half * 8];
            bf16x8 af1 = *(const bf16x8*)&fb[(size_t)(i0 + it * 32 + l31) * 32 + 16 + half * 8];
            f32x16 sacc = __builtin_amdgcn_mfma_f32_32x32x16_bf16(
                af0, gf0, (f32x16)0.f, 0, 0, 0);
            sacc = __builtin_amdgcn_mfma_f32_32x32x16_bf16(af1, gf1, sacc, 0, 0, 0);

            float p0  = __expf(sacc[0]),  p1  = __expf(sacc[1]);
            float p2  = __expf(sacc[2]),  p3  = __expf(sacc[3]);
            float p4  = __expf(sacc[4]),  p5  = __expf(sacc[5]);
            float p6  = __expf(sacc[6]),  p7  = __expf(sacc[7]);
            float p8  = __expf(sacc[8]),  p9  = __expf(sacc[9]);
            float p10 = __expf(sacc[10]), p11 = __expf(sacc[11]);
            float p12 = __expf(sacc[12]), p13 = __expf(sacc[13]);
            float p14 = __expf(sacc[14]), p15 = __expf(sacc[15]);
            lacc += ((p0 + p1) + (p2 + p3)) + ((p4 + p5) + (p6 + p7))
                  + ((p8 + p9) + (p10 + p11)) + ((p12 + p13) + (p14 + p15));

            unsigned o0 = pack2bf(p0,  p1),  o1 = pack2bf(p2,  p3);
            unsigned o2 = pack2bf(p4,  p5),  o3 = pack2bf(p6,  p7);
            unsigned o4 = pack2bf(p8,  p9),  o5 = pack2bf(p10, p11);
            unsigned o6 = pack2bf(p12, p13), o7 = pack2bf(p14, p15);
            unsigned e0 = __shfl_xor((int)o0, 32), e1 = __shfl_xor((int)o1, 32);
            unsigned e2 = __shfl_xor((int)o2, 32), e3 = __shfl_xor((int)o3, 32);
            unsigned e4 = __shfl_xor((int)o4, 32), e5 = __shfl_xor((int)o5, 32);
            unsigned e6 = __shfl_xor((int)o6, 32), e7 = __shfl_xor((int)o7, 32);

            u32x4 pw0, pw1;
            pw0.x = half ? e2 : o0;  pw0.y = half ? e3 : o1;
            pw0.z = half ? o2 : e0;  pw0.w = half ? o3 : e1;
            pw1.x = half ? e6 : o4;  pw1.y = half ? e7 : o5;
            pw1.z = half ? o6 : e4;  pw1.w = half ? o7 : e5;
            bf16x8 pf0 = __builtin_bit_cast(bf16x8, pw0);
            bf16x8 pf1 = __builtin_bit_cast(bf16x8, pw1);

            // ---- PV: c-range [cg*128, +128) x wave's 32 j ----
#pragma unroll
            for (int kb = 0; kb < 2; ++kb) {
                int unit = it * 4 + kb * 2 + half;
                bf16x8 pf = kb ? pf1 : pf0;
#pragma unroll
                for (int ct = 0; ct < 4; ++ct) {
                    int c = cg * 128 + ct * 32 + l31;
                    bf16x8 afr = *(const bf16x8*)&hvT[cur][c][(unit ^ (c & 7)) * 8];
                    acc[ct] = __builtin_amdgcn_mfma_f32_32x32x16_bf16(
                        afr, pf, acc[ct], 0, 0, 0);
                }
            }
        }
    }

    // ---- write bf16 partials ----
    unsigned short* ob = o_part + (size_t)bs * C_ * N_;
#pragma unroll
    for (int ct = 0; ct < 4; ++ct) {
        f32x16 a = acc[ct];
#pragma unroll
        for (int r = 0; r < 16; ++r) {
            int c = cg * 128 + ct * 32 + (r & 3) + 8 * (r >> 2) + 4 * half;
            int j = jb + l31;
            ob[(size_t)c * N_ + j] = f2bf(a[r]);
        }
    }
    // ---- column sums (cg==0 waves; halves hold complementary i-rows) ----
    if (cg == 0) {
        float lsum = lacc + __shfl_xor(lacc, 32);
        if (half == 0)
            l_part[(size_t)bs * N_ + jb + l31] = lsum;
    }
}

// ---------------- combine: sum splits, normalize, residual ----------------
__global__ __launch_bounds__(256) void combine_kernel(
    const unsigned short* __restrict__ o_part, const float* __restrict__ l_part,
    const float* __restrict__ x, const float* __restrict__ gamma,
    float* __restrict__ out)
{
    int j = blockIdx.x * 256 + threadIdx.x;
    int b = blockIdx.z;
    float l = 0.f;
#pragma unroll
    for (int s = 0; s < SPLITS; ++s)
        l += l_part[(size_t)(b * SPLITS + s) * N_ + j];
    float inv = 1.f / l;
    float gm = gamma[0];
#pragma unroll
    for (int cc = 0; cc < 4; ++cc) {
        int c = blockIdx.y * 4 + cc;
        float o = 0.f;
#pragma unroll
        for (int s = 0; s < SPLITS; ++s)
            o += bf2f(o_part[((size_t)(b * SPLITS + s) * C_ + c) * N_ + j]);
        size_t idx = ((size_t)b * C_ + c) * N_ + j;
        out[idx] = gm * o * inv + x[idx];
    }
}

extern "C" void kernel_launch(void* const* d_in, const int* in_sizes, int n_in,
                              void* d_out, int out_size, void* d_ws, size_t ws_size,
                              hipStream_t stream) {
    const float* x     = (const float*)d_in[0];
    const float* Wq    = (const float*)d_in[1];
    const float* Wk    = (const float*)d_in[2];
    const float* Wv    = (const float*)d_in[3];
    const float* gamma = (const float*)d_in[4];
    float* out = (float*)d_out;

    char* ws = (char*)d_ws;
    unsigned short* o_part = (unsigned short*)ws;                     // 16.8 MB bf16
    float* l_part = (float*)(o_part + (size_t)SPLITS * B_ * C_ * N_); // 128 KB
    unsigned short* fTg = (unsigned short*)(l_part + (size_t)SPLITS * B_ * N_); // 1 MB
    unsigned short* g   = fTg + (size_t)B_ * C8_ * N_;                // 1 MB
    unsigned short* hv  = g   + (size_t)B_ * C8_ * N_;                // 8 MB
    unsigned short* Wbf = hv  + (size_t)B_ * C_  * N_;                // 160 KB
    unsigned short* xT  = Wbf + (size_t)(C_ + 2 * C8_) * C_;          // 8.4 MB

    prep_w_kernel<<<dim3(80), 256, 0, stream>>>(Wq, Wk, Wv, Wbf);
    prep_x_kernel<<<dim3(N_ / 64, C_ / 64, B_), 256, 0, stream>>>(x, xT);

    proj_mfma_kernel<<<dim3(N_ / 32, B_), 256, 0, stream>>>(Wbf, xT, fTg, g, hv);

    flash_kernel<<<dim3(N_ / 64, SPLITS, B_), 256, 0, stream>>>(
        fTg, g, hv, o_part, l_part);

    combine_kernel<<<dim3(N_ / 256, C_ / 4, B_), 256, 0, stream>>>(o_part, l_part, x, gamma, out);
}